// Round 8
// baseline (364.939 us; speedup 1.0000x reference)
//
#include <hip/hip_runtime.h>
#include <hip/hip_bf16.h>
#include <math.h>

#define D_MODEL 512
#define N_HEADS 8
#define D_HEAD 64
#define D_FF 2048
#define SEQ 2048
#define BATCH 4
#define NTOK (BATCH * SEQ)
#define QSCALE 0.04419417382415922f          // 1/sqrt(512)
#define QSCALE_L2E (-QSCALE * 1.44269504089f) // fold -log2(e)*scale into Q

typedef unsigned short ushort_t;
typedef __attribute__((ext_vector_type(8))) short short8;
typedef __attribute__((ext_vector_type(4))) short short4v;
typedef __attribute__((ext_vector_type(4))) float float4v;

static __device__ __forceinline__ ushort_t f2bf(float f) {
    union { float f; unsigned int i; } c; c.f = f;
    unsigned int i = c.i;
    unsigned int r = (i + 0x7FFFu + ((i >> 16) & 1u)) >> 16;   // RNE
    return (ushort_t)r;
}

static __device__ __forceinline__ unsigned int pack2bf(float a, float b) {
    union { __hip_bfloat162 h; unsigned int u; } c;
    c.h = __float22bfloat162_rn(make_float2(a, b));
    return c.u;
}

// sigmoid with scale pre-folded: input st = -s*scale*log2e  ->  1/(1+2^st)
static __device__ __forceinline__ float sig2(float x) {
    return __builtin_amdgcn_rcpf(1.0f + __builtin_amdgcn_exp2f(x));
}

// ------------- weights -> bf16 transposed [N][K], LDS-tiled (coalesced both sides) -------
__global__ __launch_bounds__(256) void k_prep_weights(const float* __restrict__ Wq,
                                                      const float* __restrict__ Wk,
                                                      const float* __restrict__ Wv,
                                                      const float* __restrict__ W1,
                                                      const float* __restrict__ W2,
                                                      ushort_t* __restrict__ Wqkvt,
                                                      ushort_t* __restrict__ W1t,
                                                      ushort_t* __restrict__ W2t) {
    __shared__ ushort_t tile[64][66];
    int bid = blockIdx.x;
    const float* src; ushort_t* dst; int K, N, tk, tn;
    if (bid < 192) {
        int m = bid >> 6, r = bid & 63;
        src = (m == 0) ? Wq : ((m == 1) ? Wk : Wv);
        dst = Wqkvt + (size_t)m * 512 * 512; K = 512; N = 512; tk = r >> 3; tn = r & 7;
    } else if (bid < 448) {
        int r = bid - 192; src = W1; dst = W1t; K = 512; N = 2048; tk = r >> 5; tn = r & 31;
    } else {
        int r = bid - 448; src = W2; dst = W2t; K = 2048; N = 512; tk = r >> 3; tn = r & 7;
    }
    int k0 = tk * 64, n0 = tn * 64;
    int rr = threadIdx.x >> 6, c = threadIdx.x & 63;
#pragma unroll
    for (int i = 0; i < 16; i++) {
        int row = i * 4 + rr;
        tile[row][c] = f2bf(src[(size_t)(k0 + row) * N + n0 + c]);
    }
    __syncthreads();
#pragma unroll
    for (int i = 0; i < 16; i++) {
        int row = i * 4 + rr;   // n-local
        dst[(size_t)(n0 + row) * K + k0 + c] = tile[c][row];
    }
}

// ---------------- layernorm: one wave per 512-wide row, out bf16 ----------------
__global__ __launch_bounds__(256) void k_layernorm(const float* __restrict__ X,
                                                   const float* __restrict__ g,
                                                   const float* __restrict__ be,
                                                   ushort_t* __restrict__ Out) {
    int row  = blockIdx.x * 4 + (threadIdx.x >> 6);
    int lane = threadIdx.x & 63;
    const float* x = X + (size_t)row * D_MODEL + lane * 8;
    float4 v0 = ((const float4*)x)[0];
    float4 v1 = ((const float4*)x)[1];
    float vals[8] = {v0.x, v0.y, v0.z, v0.w, v1.x, v1.y, v1.z, v1.w};
    float s = 0.f, sq = 0.f;
#pragma unroll
    for (int j = 0; j < 8; j++) { s += vals[j]; sq += vals[j] * vals[j]; }
#pragma unroll
    for (int off = 32; off; off >>= 1) { s += __shfl_xor(s, off); sq += __shfl_xor(sq, off); }
    float mu  = s * (1.0f / D_MODEL);
    float var = sq * (1.0f / D_MODEL) - mu * mu;
    float inv = rsqrtf(var + 1e-5f);
    const float* gp  = g  + lane * 8;
    const float* bp  = be + lane * 8;
    float4 g0 = ((const float4*)gp)[0], g1v = ((const float4*)gp)[1];
    float4 b0 = ((const float4*)bp)[0], b1v = ((const float4*)bp)[1];
    float gs[8] = {g0.x, g0.y, g0.z, g0.w, g1v.x, g1v.y, g1v.z, g1v.w};
    float bs[8] = {b0.x, b0.y, b0.z, b0.w, b1v.x, b1v.y, b1v.z, b1v.w};
    ushort_t o[8];
#pragma unroll
    for (int j = 0; j < 8; j++) o[j] = f2bf((vals[j] - mu) * inv * gs[j] + bs[j]);
    ushort_t* op = Out + (size_t)row * D_MODEL + lane * 8;
    *(uint4*)op = *(uint4*)o;
}

// ======== m97-style GEMM core: 128xBN tile, BK=32, global_load_lds double-buffer =========
static __device__ __forceinline__ void stage_tile(const ushort_t* __restrict__ G, int K,
                                                  ushort_t* L, int nchunks, int koff,
                                                  int w, int l) {
#pragma unroll
    for (int n = w; n < nchunks; n += 4) {
        const ushort_t* g = G + (size_t)(n * 16 + (l >> 2)) * K + koff + (l & 3) * 8;
        __builtin_amdgcn_global_load_lds((const __attribute__((address_space(1))) void*)g,
                                         (__attribute__((address_space(3))) void*)(L + n * 512),
                                         16, 0, 0);
    }
}

template <int JW>
static __device__ __forceinline__ void gemm_core2(const ushort_t* __restrict__ A,
                                                  const ushort_t* __restrict__ Bt,
                                                  int K, int m0, int n0,
                                                  ushort_t* As, ushort_t* Bs,
                                                  float4v acc[4][JW]) {
    const int BBUF = JW * 1024;
    int t = threadIdx.x, w = t >> 6, l = t & 63, q = l >> 4, lm = l & 15;
    int mb = (w & 1) * 64, nb = (w >> 1) * (JW * 16);
    const ushort_t* Ab = A + (size_t)m0 * K;
    const ushort_t* Bb = Bt + (size_t)n0 * K;
    int T = K >> 5;

    stage_tile(Ab, K, As, 8, 0, w, l);
    stage_tile(Bb, K, Bs, 2 * JW, 0, w, l);
    __syncthreads();

    for (int kt = 0; kt < T; kt++) {
        int cur = kt & 1;
        if (kt + 1 < T) {
            stage_tile(Ab, K, As + (1 - cur) * 4096, 8, (kt + 1) * 32, w, l);
            stage_tile(Bb, K, Bs + (1 - cur) * BBUF, 2 * JW, (kt + 1) * 32, w, l);
        }
        const ushort_t* asb = As + cur * 4096;
        const ushort_t* bsb = Bs + cur * BBUF;
        short8 a[4], b[JW];
#pragma unroll
        for (int i = 0; i < 4; i++) a[i] = *(const short8*)&asb[(mb + 16 * i + lm) * 32 + q * 8];
#pragma unroll
        for (int j = 0; j < JW; j++) b[j] = *(const short8*)&bsb[(nb + 16 * j + lm) * 32 + q * 8];
#pragma unroll
        for (int i = 0; i < 4; i++)
#pragma unroll
            for (int j = 0; j < JW; j++)
                acc[i][j] = __builtin_amdgcn_mfma_f32_16x16x32_bf16(a[i], b[j], acc[i][j], 0, 0, 0);
        __syncthreads();
    }
}

// ---------------- fused QKV projection (N=1536): q,k head-layout; v transposed ------------
__global__ __launch_bounds__(256) void k_gemm_qkv(const ushort_t* __restrict__ A,
                                                  const ushort_t* __restrict__ Bt,
                                                  const float* __restrict__ bq,
                                                  const float* __restrict__ bk,
                                                  const float* __restrict__ bv,
                                                  ushort_t* __restrict__ qb,
                                                  ushort_t* __restrict__ kb,
                                                  ushort_t* __restrict__ vt) {
    __shared__ __align__(16) ushort_t As[8192];
    __shared__ __align__(16) ushort_t Bs[8192];
    int m0 = blockIdx.x * 128, n0 = blockIdx.y * 128;
    float4v acc[4][4];
#pragma unroll
    for (int i = 0; i < 4; i++)
#pragma unroll
        for (int j = 0; j < 4; j++) acc[i][j] = (float4v){0.f, 0.f, 0.f, 0.f};
    gemm_core2<4>(A, Bt, D_MODEL, m0, n0, As, Bs, acc);

    int t = threadIdx.x, w = t >> 6, l = t & 63, q = l >> 4, lm = l & 15;
    int mb = (w & 1) * 64, nb = (w >> 1) * 64;
    int mat = n0 >> 9, c0 = n0 & 511;
    const float* bias = (mat == 0) ? bq : ((mat == 1) ? bk : bv);
#pragma unroll
    for (int j = 0; j < 4; j++) {
        int cl = c0 + nb + 16 * j + lm;
        int hh = cl >> 6, dh = cl & 63;
        float bvv = bias[cl];
#pragma unroll
        for (int i = 0; i < 4; i++) {
            int mr0 = m0 + mb + 16 * i + q * 4;
            int bb = mr0 >> 11, ss0 = mr0 & (SEQ - 1);
            if (mat == 2) {
                union { ushort_t s[4]; uint2 v; } pk;
#pragma unroll
                for (int r = 0; r < 4; r++) pk.s[r] = f2bf(acc[i][j][r] + bvv);
                *(uint2*)&vt[((size_t)(bb * N_HEADS + hh) * D_HEAD + dh) * SEQ + ss0] = pk.v;
            } else {
                ushort_t* dst = (mat == 0) ? qb : kb;
                float sc = (mat == 0) ? QSCALE_L2E : 1.0f;
#pragma unroll
                for (int r = 0; r < 4; r++)
                    dst[((size_t)(bb * N_HEADS + hh) * SEQ + ss0 + r) * D_HEAD + dh] =
                        f2bf((acc[i][j][r] + bvv) * sc);
            }
        }
    }
}

// ---------------- FFN1: relu(yn @ W1 + b1) -> bf16 row-major ------------------------------
__global__ __launch_bounds__(256) void k_gemm_ffn1(const ushort_t* __restrict__ A,
                                                   const ushort_t* __restrict__ Bt,
                                                   const float* __restrict__ b1,
                                                   ushort_t* __restrict__ hb) {
    __shared__ __align__(16) ushort_t As[8192];
    __shared__ __align__(16) ushort_t Bs[8192];
    int m0 = blockIdx.x * 128, n0 = blockIdx.y * 128;
    float4v acc[4][4];
#pragma unroll
    for (int i = 0; i < 4; i++)
#pragma unroll
        for (int j = 0; j < 4; j++) acc[i][j] = (float4v){0.f, 0.f, 0.f, 0.f};
    gemm_core2<4>(A, Bt, D_MODEL, m0, n0, As, Bs, acc);

    int t = threadIdx.x, w = t >> 6, l = t & 63, q = l >> 4, lm = l & 15;
    int mb = (w & 1) * 64, nb = (w >> 1) * 64;
#pragma unroll
    for (int j = 0; j < 4; j++) {
        int cl = n0 + nb + 16 * j + lm;
        float bvv = b1[cl];
#pragma unroll
        for (int i = 0; i < 4; i++) {
            int mr0 = m0 + mb + 16 * i + q * 4;
#pragma unroll
            for (int r = 0; r < 4; r++)
                hb[(size_t)(mr0 + r) * D_FF + cl] = f2bf(fmaxf(acc[i][j][r] + bvv, 0.f));
        }
    }
}

// ---------------- FFN2: hb @ W2 + b2 + residual -> f32 out (128x64 tile) ------------------
__global__ __launch_bounds__(256) void k_gemm_ffn2(const ushort_t* __restrict__ A,
                                                   const ushort_t* __restrict__ Bt,
                                                   const float* __restrict__ b2,
                                                   const float* __restrict__ res,
                                                   float* __restrict__ out) {
    __shared__ __align__(16) ushort_t As[8192];
    __shared__ __align__(16) ushort_t Bs[4096];
    int m0 = blockIdx.x * 128, n0 = blockIdx.y * 64;
    float4v acc[4][2];
#pragma unroll
    for (int i = 0; i < 4; i++)
#pragma unroll
        for (int j = 0; j < 2; j++) acc[i][j] = (float4v){0.f, 0.f, 0.f, 0.f};
    gemm_core2<2>(A, Bt, D_FF, m0, n0, As, Bs, acc);

    int t = threadIdx.x, w = t >> 6, l = t & 63, q = l >> 4, lm = l & 15;
    int mb = (w & 1) * 64, nb = (w >> 1) * 32;
#pragma unroll
    for (int j = 0; j < 2; j++) {
        int cl = n0 + nb + 16 * j + lm;
        float bvv = b2[cl];
#pragma unroll
        for (int i = 0; i < 4; i++) {
            int mr0 = m0 + mb + 16 * i + q * 4;
#pragma unroll
            for (int r = 0; r < 4; r++) {
                size_t idx = (size_t)(mr0 + r) * D_MODEL + cl;
                out[idx] = acc[i][j][r] + bvv + res[idx];
            }
        }
    }
}

// ---------------- fused sigmoid attention v11: barrier-free, direct-global K/V ------------
// Same geometry as v9/v10 (512 thr / 8 waves, 128-Q block, 128-t tile, grid 16x32).
// CHANGE: K/V LDS staging DELETED — each wave loads its kf/vf fragments straight from
// global (L2/L3-served: per-XCD instantaneous working set ~2MB of in-flight tiles).
// Zero __syncthreads in the main loop, zero ds_write, zero double-buffer, bank conflicts
// gone (6.36M -> ~0; only the final O-reduction uses LDS). Waves run fully independent;
// TLP (4 waves/SIMD) + unobstructed compiler pipelining hide VMEM latency.
// K coalescing: 4-lane groups cover full 64B lines (zero overfetch). V: 32B/line (L2-hit).
// Fragment layouts byte-identical to v10 — pure change of data source.
__global__ __launch_bounds__(512, 4) void k_attention(const ushort_t* __restrict__ Q,
                                                      const ushort_t* __restrict__ Kb,
                                                      const ushort_t* __restrict__ Vt,
                                                      const float* __restrict__ X,
                                                      float* __restrict__ Y) {
    __shared__ __align__(16) float Osum[128 * 68];     // 34816 B — only block-shared state

    const int NIT = SEQ / 128;                         // 16

    int bh = blockIdx.y;
    int b = bh >> 3, h = bh & 7;
    size_t base = (size_t)bh * SEQ * D_HEAD;
    int s0 = blockIdx.x * 128;
    int t = threadIdx.x, w = t >> 6, l = t & 63, q = l >> 4, lm = l & 15;
    int g = w >> 1, th = w & 1;

    // Q fragments in registers: rows s0 + 32g + 16nt + lm
    short8 qf[2][2];
#pragma unroll
    for (int nt = 0; nt < 2; nt++)
#pragma unroll
        for (int kc = 0; kc < 2; kc++) {
            const ushort_t* qg = Q + base + (size_t)(s0 + 32 * g + 16 * nt + lm) * D_HEAD + kc * 32 + q * 8;
            uint4 u = *(const uint4*)qg;
            qf[nt][kc] = *(const short8*)&u;
        }

    // O^T partials: o[nt][dj], lane holds O[s=s0+32g+16nt+lm][d=16dj+4q+r] (t-half partial)
    float4v o[2][4];
#pragma unroll
    for (int nt = 0; nt < 2; nt++)
#pragma unroll
        for (int dj = 0; dj < 4; dj++) o[nt][dj] = (float4v){0.f, 0.f, 0.f, 0.f};

    // per-wave global fragment bases (this wave's t-half)
    // kf[mt][kc] @ Kb + base + (tt*128 + 64*th + 16*mt + lm)*64 + kc*32 + q*8   (16B)
    // vf[mt][dj] @ Vt + base + (16*dj + lm)*SEQ + tt*128 + 64*th + 16*mt + 4*q (8B)
    const ushort_t* kgw = Kb + base + (size_t)(64 * th + lm) * D_HEAD + q * 8;
    const ushort_t* vgw = Vt + base + (size_t)lm * SEQ + 64 * th + 4 * q;

    for (int tt = 0; tt < NIT; tt++) {
        const ushort_t* kp = kgw + (size_t)tt * 128 * D_HEAD;
        const ushort_t* vp = vgw + tt * 128;

#pragma unroll
        for (int mt = 0; mt < 4; mt++) {
            // --- K fragments direct from global ---
            short8 kf0, kf1;
            {
                uint4 u0 = *(const uint4*)(kp + (size_t)(16 * mt) * D_HEAD);
                uint4 u1 = *(const uint4*)(kp + (size_t)(16 * mt) * D_HEAD + 32);
                kf0 = *(const short8*)&u0;
                kf1 = *(const short8*)&u1;
            }
            // --- S^T = K Q~^T : S~[t=tt*128+64th+16mt+4q+r][s=s0+32g+16nt+lm] ---
            float4v st[2];
            st[0] = (float4v){0.f, 0.f, 0.f, 0.f};
            st[1] = (float4v){0.f, 0.f, 0.f, 0.f};
#pragma unroll
            for (int nt = 0; nt < 2; nt++) {
                st[nt] = __builtin_amdgcn_mfma_f32_16x16x32_bf16(kf0, qf[nt][0], st[nt], 0, 0, 0);
                st[nt] = __builtin_amdgcn_mfma_f32_16x16x32_bf16(kf1, qf[nt][1], st[nt], 0, 0, 0);
            }
            // --- sigmoid -> packed register P-fragments (16x16x16 B-layout: n=lm, k=4q+r) ---
            short4v pf[2];
#pragma unroll
            for (int nt = 0; nt < 2; nt++) {
                union { unsigned int u[2]; short4v v; } pk;
                pk.u[0] = pack2bf(sig2(st[nt][0]), sig2(st[nt][1]));
                pk.u[1] = pack2bf(sig2(st[nt][2]), sig2(st[nt][3]));
                pf[nt] = pk.v;
            }
            // --- O^T += V^T P : A = V^T frag direct from global; K=16 MFMA ---
#pragma unroll
            for (int dj = 0; dj < 4; dj++) {
                short4v vf = *(const short4v*)(vp + (size_t)(16 * dj) * SEQ + 16 * mt);
#pragma unroll
                for (int nt = 0; nt < 2; nt++)
                    o[nt][dj] = __builtin_amdgcn_mfma_f32_16x16x16bf16_1k(vf, pf[nt], o[nt][dj], 0, 0, 0);
            }
        }
    }

    // --- pair-wave O reduction into Osum (float4; stride 68 keeps 16B alignment) ---
    if (th == 0) {
#pragma unroll
        for (int nt = 0; nt < 2; nt++)
#pragma unroll
            for (int dj = 0; dj < 4; dj++) {
                float4v v = o[nt][dj];
                *(float4*)&Osum[(32 * g + 16 * nt + lm) * 68 + 16 * dj + 4 * q] =
                    make_float4(v[0], v[1], v[2], v[3]);
            }
    }
    __syncthreads();
    if (th == 1) {
#pragma unroll
        for (int nt = 0; nt < 2; nt++)
#pragma unroll
            for (int dj = 0; dj < 4; dj++) {
                float* p = &Osum[(32 * g + 16 * nt + lm) * 68 + 16 * dj + 4 * q];
                float4 old = *(float4*)p;
                float4v v = o[nt][dj];
                *(float4*)p = make_float4(old.x + v[0], old.y + v[1], old.z + v[2], old.w + v[3]);
            }
    }
    __syncthreads();

    // --- epilogue: Y = X + O (thread t: row t>>2, 16 cols) ---
    {
        int row = t >> 2, c0 = (t & 3) * 16;
        size_t gro = ((size_t)(b * SEQ + s0 + row)) * D_MODEL + h * D_HEAD + c0;
        const float* xp = X + gro;
        float* yp = Y + gro;
        const float* os = &Osum[row * 68 + c0];
#pragma unroll
        for (int i = 0; i < 4; i++) {
            float4 xv = *(const float4*)(xp + i * 4);
            float4 ov = *(const float4*)(os + i * 4);
            float4 rr;
            rr.x = xv.x + ov.x; rr.y = xv.y + ov.y;
            rr.z = xv.z + ov.z; rr.w = xv.w + ov.w;
            *(float4*)(yp + i * 4) = rr;
        }
    }
}

extern "C" void kernel_launch(void* const* d_in, const int* in_sizes, int n_in,
                              void* d_out, int out_size, void* d_ws, size_t ws_size,
                              hipStream_t stream) {
    const float* x   = (const float*)d_in[0];
    const float* Wq  = (const float*)d_in[1];
    const float* bq  = (const float*)d_in[2];
    const float* Wk  = (const float*)d_in[3];
    const float* bk  = (const float*)d_in[4];
    const float* Wv  = (const float*)d_in[5];
    const float* bv  = (const float*)d_in[6];
    const float* W1  = (const float*)d_in[7];
    const float* b1  = (const float*)d_in[8];
    const float* W2  = (const float*)d_in[9];
    const float* b2  = (const float*)d_in[10];
    const float* g1  = (const float*)d_in[11];
    const float* be1 = (const float*)d_in[12];
    const float* g2  = (const float*)d_in[13];
    const float* be2 = (const float*)d_in[14];
    float* out = (float*)d_out;

    char* p = (char*)d_ws;
    ushort_t* xn    = (ushort_t*)p; p += (size_t)NTOK * D_MODEL * 2;
    ushort_t* yn    = (ushort_t*)p; p += (size_t)NTOK * D_MODEL * 2;
    float*    y     = (float*)p;    p += (size_t)NTOK * D_MODEL * 4;
    ushort_t* qb    = (ushort_t*)p; p += (size_t)NTOK * D_MODEL * 2;
    ushort_t* kb    = (ushort_t*)p; p += (size_t)NTOK * D_MODEL * 2;
    ushort_t* vt    = (ushort_t*)p; p += (size_t)NTOK * D_MODEL * 2;
    ushort_t* hb    = (ushort_t*)p; p += (size_t)NTOK * D_FF * 2;
    ushort_t* Wqkvt = (ushort_t*)p; p += (size_t)3 * D_MODEL * D_MODEL * 2;
    ushort_t* W1t   = (ushort_t*)p; p += (size_t)D_MODEL * D_FF * 2;
    ushort_t* W2t   = (ushort_t*)p; p += (size_t)D_FF * D_MODEL * 2;

    k_prep_weights<<<704, 256, 0, stream>>>(Wq, Wk, Wv, W1, W2, Wqkvt, W1t, W2t);

    k_layernorm<<<NTOK / 4, 256, 0, stream>>>(x, g1, be1, xn);

    dim3 gq(NTOK / 128, (3 * D_MODEL) / 128);
    k_gemm_qkv<<<gq, 256, 0, stream>>>(xn, Wqkvt, bq, bk, bv, qb, kb, vt);

    dim3 ga(SEQ / 128, BATCH * N_HEADS);
    k_attention<<<ga, 512, 0, stream>>>(qb, kb, vt, x, y);

    k_layernorm<<<NTOK / 4, 256, 0, stream>>>(y, g2, be2, yn);

    dim3 g1d(NTOK / 128, D_FF / 128);
    k_gemm_ffn1<<<g1d, 256, 0, stream>>>(yn, W1t, b1, hb);
    dim3 g2d(NTOK / 128, D_MODEL / 64);
    k_gemm_ffn2<<<g2d, 256, 0, stream>>>(hb, W2t, b2, y, out);
}

// Round 9
// 246.658 us; speedup vs baseline: 1.4795x; 1.4795x over previous
//
#include <hip/hip_runtime.h>
#include <hip/hip_bf16.h>
#include <math.h>

#define D_MODEL 512
#define N_HEADS 8
#define D_HEAD 64
#define D_FF 2048
#define SEQ 2048
#define BATCH 4
#define NTOK (BATCH * SEQ)
#define QSCALE 0.04419417382415922f          // 1/sqrt(512)
#define QSCALE_L2E (-QSCALE * 1.44269504089f) // fold -log2(e)*scale into Q

typedef unsigned short ushort_t;
typedef __attribute__((ext_vector_type(8))) short short8;
typedef __attribute__((ext_vector_type(4))) short short4v;
typedef __attribute__((ext_vector_type(4))) float float4v;

static __device__ __forceinline__ ushort_t f2bf(float f) {
    union { float f; unsigned int i; } c; c.f = f;
    unsigned int i = c.i;
    unsigned int r = (i + 0x7FFFu + ((i >> 16) & 1u)) >> 16;   // RNE
    return (ushort_t)r;
}

static __device__ __forceinline__ unsigned int pack2bf(float a, float b) {
    union { __hip_bfloat162 h; unsigned int u; } c;
    c.h = __float22bfloat162_rn(make_float2(a, b));
    return c.u;
}

// sigmoid with scale pre-folded: input st = -s*scale*log2e  ->  1/(1+2^st)
static __device__ __forceinline__ float sig2(float x) {
    return __builtin_amdgcn_rcpf(1.0f + __builtin_amdgcn_exp2f(x));
}

// ------------- weights -> bf16 transposed [N][K], LDS-tiled (coalesced both sides) -------
__global__ __launch_bounds__(256) void k_prep_weights(const float* __restrict__ Wq,
                                                      const float* __restrict__ Wk,
                                                      const float* __restrict__ Wv,
                                                      const float* __restrict__ W1,
                                                      const float* __restrict__ W2,
                                                      ushort_t* __restrict__ Wqkvt,
                                                      ushort_t* __restrict__ W1t,
                                                      ushort_t* __restrict__ W2t) {
    __shared__ ushort_t tile[64][66];
    int bid = blockIdx.x;
    const float* src; ushort_t* dst; int K, N, tk, tn;
    if (bid < 192) {
        int m = bid >> 6, r = bid & 63;
        src = (m == 0) ? Wq : ((m == 1) ? Wk : Wv);
        dst = Wqkvt + (size_t)m * 512 * 512; K = 512; N = 512; tk = r >> 3; tn = r & 7;
    } else if (bid < 448) {
        int r = bid - 192; src = W1; dst = W1t; K = 512; N = 2048; tk = r >> 5; tn = r & 31;
    } else {
        int r = bid - 448; src = W2; dst = W2t; K = 2048; N = 512; tk = r >> 3; tn = r & 7;
    }
    int k0 = tk * 64, n0 = tn * 64;
    int rr = threadIdx.x >> 6, c = threadIdx.x & 63;
#pragma unroll
    for (int i = 0; i < 16; i++) {
        int row = i * 4 + rr;
        tile[row][c] = f2bf(src[(size_t)(k0 + row) * N + n0 + c]);
    }
    __syncthreads();
#pragma unroll
    for (int i = 0; i < 16; i++) {
        int row = i * 4 + rr;   // n-local
        dst[(size_t)(n0 + row) * K + k0 + c] = tile[c][row];
    }
}

// ---------------- layernorm: one wave per 512-wide row, out bf16 ----------------
__global__ __launch_bounds__(256) void k_layernorm(const float* __restrict__ X,
                                                   const float* __restrict__ g,
                                                   const float* __restrict__ be,
                                                   ushort_t* __restrict__ Out) {
    int row  = blockIdx.x * 4 + (threadIdx.x >> 6);
    int lane = threadIdx.x & 63;
    const float* x = X + (size_t)row * D_MODEL + lane * 8;
    float4 v0 = ((const float4*)x)[0];
    float4 v1 = ((const float4*)x)[1];
    float vals[8] = {v0.x, v0.y, v0.z, v0.w, v1.x, v1.y, v1.z, v1.w};
    float s = 0.f, sq = 0.f;
#pragma unroll
    for (int j = 0; j < 8; j++) { s += vals[j]; sq += vals[j] * vals[j]; }
#pragma unroll
    for (int off = 32; off; off >>= 1) { s += __shfl_xor(s, off); sq += __shfl_xor(sq, off); }
    float mu  = s * (1.0f / D_MODEL);
    float var = sq * (1.0f / D_MODEL) - mu * mu;
    float inv = rsqrtf(var + 1e-5f);
    const float* gp  = g  + lane * 8;
    const float* bp  = be + lane * 8;
    float4 g0 = ((const float4*)gp)[0], g1v = ((const float4*)gp)[1];
    float4 b0 = ((const float4*)bp)[0], b1v = ((const float4*)bp)[1];
    float gs[8] = {g0.x, g0.y, g0.z, g0.w, g1v.x, g1v.y, g1v.z, g1v.w};
    float bs[8] = {b0.x, b0.y, b0.z, b0.w, b1v.x, b1v.y, b1v.z, b1v.w};
    ushort_t o[8];
#pragma unroll
    for (int j = 0; j < 8; j++) o[j] = f2bf((vals[j] - mu) * inv * gs[j] + bs[j]);
    ushort_t* op = Out + (size_t)row * D_MODEL + lane * 8;
    *(uint4*)op = *(uint4*)o;
}

// ======== m97-style GEMM core: 128xBN tile, BK=32, global_load_lds double-buffer =========
static __device__ __forceinline__ void stage_tile(const ushort_t* __restrict__ G, int K,
                                                  ushort_t* L, int nchunks, int koff,
                                                  int w, int l) {
#pragma unroll
    for (int n = w; n < nchunks; n += 4) {
        const ushort_t* g = G + (size_t)(n * 16 + (l >> 2)) * K + koff + (l & 3) * 8;
        __builtin_amdgcn_global_load_lds((const __attribute__((address_space(1))) void*)g,
                                         (__attribute__((address_space(3))) void*)(L + n * 512),
                                         16, 0, 0);
    }
}

template <int JW>
static __device__ __forceinline__ void gemm_core2(const ushort_t* __restrict__ A,
                                                  const ushort_t* __restrict__ Bt,
                                                  int K, int m0, int n0,
                                                  ushort_t* As, ushort_t* Bs,
                                                  float4v acc[4][JW]) {
    const int BBUF = JW * 1024;
    int t = threadIdx.x, w = t >> 6, l = t & 63, q = l >> 4, lm = l & 15;
    int mb = (w & 1) * 64, nb = (w >> 1) * (JW * 16);
    const ushort_t* Ab = A + (size_t)m0 * K;
    const ushort_t* Bb = Bt + (size_t)n0 * K;
    int T = K >> 5;

    stage_tile(Ab, K, As, 8, 0, w, l);
    stage_tile(Bb, K, Bs, 2 * JW, 0, w, l);
    __syncthreads();

    for (int kt = 0; kt < T; kt++) {
        int cur = kt & 1;
        if (kt + 1 < T) {
            stage_tile(Ab, K, As + (1 - cur) * 4096, 8, (kt + 1) * 32, w, l);
            stage_tile(Bb, K, Bs + (1 - cur) * BBUF, 2 * JW, (kt + 1) * 32, w, l);
        }
        const ushort_t* asb = As + cur * 4096;
        const ushort_t* bsb = Bs + cur * BBUF;
        short8 a[4], b[JW];
#pragma unroll
        for (int i = 0; i < 4; i++) a[i] = *(const short8*)&asb[(mb + 16 * i + lm) * 32 + q * 8];
#pragma unroll
        for (int j = 0; j < JW; j++) b[j] = *(const short8*)&bsb[(nb + 16 * j + lm) * 32 + q * 8];
#pragma unroll
        for (int i = 0; i < 4; i++)
#pragma unroll
            for (int j = 0; j < JW; j++)
                acc[i][j] = __builtin_amdgcn_mfma_f32_16x16x32_bf16(a[i], b[j], acc[i][j], 0, 0, 0);
        __syncthreads();
    }
}

// ---------------- fused QKV projection (N=1536): q,k head-layout; v transposed ------------
__global__ __launch_bounds__(256) void k_gemm_qkv(const ushort_t* __restrict__ A,
                                                  const ushort_t* __restrict__ Bt,
                                                  const float* __restrict__ bq,
                                                  const float* __restrict__ bk,
                                                  const float* __restrict__ bv,
                                                  ushort_t* __restrict__ qb,
                                                  ushort_t* __restrict__ kb,
                                                  ushort_t* __restrict__ vt) {
    __shared__ __align__(16) ushort_t As[8192];
    __shared__ __align__(16) ushort_t Bs[8192];
    int m0 = blockIdx.x * 128, n0 = blockIdx.y * 128;
    float4v acc[4][4];
#pragma unroll
    for (int i = 0; i < 4; i++)
#pragma unroll
        for (int j = 0; j < 4; j++) acc[i][j] = (float4v){0.f, 0.f, 0.f, 0.f};
    gemm_core2<4>(A, Bt, D_MODEL, m0, n0, As, Bs, acc);

    int t = threadIdx.x, w = t >> 6, l = t & 63, q = l >> 4, lm = l & 15;
    int mb = (w & 1) * 64, nb = (w >> 1) * 64;
    int mat = n0 >> 9, c0 = n0 & 511;
    const float* bias = (mat == 0) ? bq : ((mat == 1) ? bk : bv);
#pragma unroll
    for (int j = 0; j < 4; j++) {
        int cl = c0 + nb + 16 * j + lm;
        int hh = cl >> 6, dh = cl & 63;
        float bvv = bias[cl];
#pragma unroll
        for (int i = 0; i < 4; i++) {
            int mr0 = m0 + mb + 16 * i + q * 4;
            int bb = mr0 >> 11, ss0 = mr0 & (SEQ - 1);
            if (mat == 2) {
                union { ushort_t s[4]; uint2 v; } pk;
#pragma unroll
                for (int r = 0; r < 4; r++) pk.s[r] = f2bf(acc[i][j][r] + bvv);
                *(uint2*)&vt[((size_t)(bb * N_HEADS + hh) * D_HEAD + dh) * SEQ + ss0] = pk.v;
            } else {
                ushort_t* dst = (mat == 0) ? qb : kb;
                float sc = (mat == 0) ? QSCALE_L2E : 1.0f;
#pragma unroll
                for (int r = 0; r < 4; r++)
                    dst[((size_t)(bb * N_HEADS + hh) * SEQ + ss0 + r) * D_HEAD + dh] =
                        f2bf((acc[i][j][r] + bvv) * sc);
            }
        }
    }
}

// ---------------- FFN1: relu(yn @ W1 + b1) -> bf16 row-major ------------------------------
__global__ __launch_bounds__(256) void k_gemm_ffn1(const ushort_t* __restrict__ A,
                                                   const ushort_t* __restrict__ Bt,
                                                   const float* __restrict__ b1,
                                                   ushort_t* __restrict__ hb) {
    __shared__ __align__(16) ushort_t As[8192];
    __shared__ __align__(16) ushort_t Bs[8192];
    int m0 = blockIdx.x * 128, n0 = blockIdx.y * 128;
    float4v acc[4][4];
#pragma unroll
    for (int i = 0; i < 4; i++)
#pragma unroll
        for (int j = 0; j < 4; j++) acc[i][j] = (float4v){0.f, 0.f, 0.f, 0.f};
    gemm_core2<4>(A, Bt, D_MODEL, m0, n0, As, Bs, acc);

    int t = threadIdx.x, w = t >> 6, l = t & 63, q = l >> 4, lm = l & 15;
    int mb = (w & 1) * 64, nb = (w >> 1) * 64;
#pragma unroll
    for (int j = 0; j < 4; j++) {
        int cl = n0 + nb + 16 * j + lm;
        float bvv = b1[cl];
#pragma unroll
        for (int i = 0; i < 4; i++) {
            int mr0 = m0 + mb + 16 * i + q * 4;
#pragma unroll
            for (int r = 0; r < 4; r++)
                hb[(size_t)(mr0 + r) * D_FF + cl] = f2bf(fmaxf(acc[i][j][r] + bvv, 0.f));
        }
    }
}

// ---------------- FFN2: hb @ W2 + b2 + residual -> f32 out (128x64 tile) ------------------
__global__ __launch_bounds__(256) void k_gemm_ffn2(const ushort_t* __restrict__ A,
                                                   const ushort_t* __restrict__ Bt,
                                                   const float* __restrict__ b2,
                                                   const float* __restrict__ res,
                                                   float* __restrict__ out) {
    __shared__ __align__(16) ushort_t As[8192];
    __shared__ __align__(16) ushort_t Bs[4096];
    int m0 = blockIdx.x * 128, n0 = blockIdx.y * 64;
    float4v acc[4][2];
#pragma unroll
    for (int i = 0; i < 4; i++)
#pragma unroll
        for (int j = 0; j < 2; j++) acc[i][j] = (float4v){0.f, 0.f, 0.f, 0.f};
    gemm_core2<2>(A, Bt, D_FF, m0, n0, As, Bs, acc);

    int t = threadIdx.x, w = t >> 6, l = t & 63, q = l >> 4, lm = l & 15;
    int mb = (w & 1) * 64, nb = (w >> 1) * 32;
#pragma unroll
    for (int j = 0; j < 2; j++) {
        int cl = n0 + nb + 16 * j + lm;
        float bvv = b2[cl];
#pragma unroll
        for (int i = 0; i < 4; i++) {
            int mr0 = m0 + mb + 16 * i + q * 4;
#pragma unroll
            for (int r = 0; r < 4; r++) {
                size_t idx = (size_t)(mr0 + r) * D_MODEL + cl;
                out[idx] = acc[i][j][r] + bvv + res[idx];
            }
        }
    }
}

// ---- attention helpers (byte-addressed, XOR-swizzled LDS) --------------------------------
static __device__ __forceinline__ void qkt_step(const char* __restrict__ ksb, int rowByte,
                                                int c0, int c1,
                                                const short8 qf[2][2], float4v st[2]) {
    short8 kf0 = *(const short8*)(ksb + rowByte + c0);
    short8 kf1 = *(const short8*)(ksb + rowByte + c1);
    st[0] = (float4v){0.f, 0.f, 0.f, 0.f};
    st[1] = (float4v){0.f, 0.f, 0.f, 0.f};
#pragma unroll
    for (int nt = 0; nt < 2; nt++) {
        st[nt] = __builtin_amdgcn_mfma_f32_16x16x32_bf16(kf0, qf[nt][0], st[nt], 0, 0, 0);
        st[nt] = __builtin_amdgcn_mfma_f32_16x16x32_bf16(kf1, qf[nt][1], st[nt], 0, 0, 0);
    }
}

static __device__ __forceinline__ void sig_pv(const char* __restrict__ vrow, int vcol,
                                              const float4v st[2], float4v o[2][4]) {
    short4v pf[2];
#pragma unroll
    for (int nt = 0; nt < 2; nt++) {
        union { unsigned int u[2]; short4v v; } pk;
        pk.u[0] = pack2bf(sig2(st[nt][0]), sig2(st[nt][1]));
        pk.u[1] = pack2bf(sig2(st[nt][2]), sig2(st[nt][3]));
        pf[nt] = pk.v;
    }
#pragma unroll
    for (int dj = 0; dj < 4; dj++) {
        short4v vf = *(const short4v*)(vrow + dj * 4096 + vcol);
#pragma unroll
        for (int nt = 0; nt < 2; nt++)
            o[nt][dj] = __builtin_amdgcn_mfma_f32_16x16x16bf16_1k(vf, pf[nt], o[nt][dj], 0, 0, 0);
    }
}

// ---------------- fused sigmoid attention v12: T2 XOR-swizzled K/V tiles ------------------
// v10 structure kept (512 thr / 8 waves, 128-Q block, KVBLK=128, mt-rotation, grid 16x32).
// CHANGE (T2, m201-pattern): padded strides (K 144B, V 272B -> bank-stride 4, measured
// 6.36M conflict cycles/dispatch ~18% of CU wall) replaced by power-of-2 row strides
// (K [128][64] @128B, V^T [64][128] @256B — row start always bank 0) + XOR swizzle
// byte_col ^= (row&7)<<4 applied on BOTH write and read sides (rule #21). Writes: each
// consecutive-8(K)/16(V)-lane group tiles one full row -> conflict-free. Reads: m201's
// verified different-rows-same-col pattern -> swizzle spreads start banks. LDS 71.7->64KB.
__global__ __launch_bounds__(512, 4) void k_attention(const ushort_t* __restrict__ Q,
                                                      const ushort_t* __restrict__ Kb,
                                                      const ushort_t* __restrict__ Vt,
                                                      const float* __restrict__ X,
                                                      float* __restrict__ Y) {
    __shared__ __align__(16) char smem[65536];
    char* Ks = smem;                                   // [2][128 rows][128B] swizzled
    char* Vs = smem + 32768;                           // [2][64 rows][256B] swizzled (V^T)
    float* Osum = (float*)smem;                        // after loop: 128 x 68 f32 (34.8 KB)

    const int KBUF = 16384;                            // bytes per K buffer
    const int VBUF = 16384;                            // bytes per V buffer
    const int NIT  = SEQ / 128;                        // 16

    int bh = blockIdx.y;
    int b = bh >> 3, h = bh & 7;
    size_t base = (size_t)bh * SEQ * D_HEAD;
    int s0 = blockIdx.x * 128;
    int t = threadIdx.x, w = t >> 6, l = t & 63, q = l >> 4, lm = l & 15;
    int g = w >> 1, th = w & 1;

    // staging (write) offsets, loop-invariant, swizzled
    int rK = t >> 3;                                   // K shot row (0..63)
    int kOff0 = rK * 128 + (((t & 7) * 16) ^ ((rK & 7) << 4));
    int kOff1 = kOff0 + 8192;                          // +64 rows, same (row&7)
    int rV = t >> 4;                                   // V shot row (0..31)
    int vOff0 = rV * 256 + (((t & 15) * 16) ^ ((rV & 7) << 4));
    int vOff1 = vOff0 + 8192;                          // +32 rows, same (row&7)

    // read offsets, swizzled
    int swz = (lm & 7) << 4;
    int kRow0 = (64 * th + lm) * 128;                  // + mt*2048
    int kc0 = (q * 16) ^ swz;
    int kc1 = kc0 ^ 64;
    int vRowB = lm * 256;                              // + dj*4096 inside sig_pv
    int vColBase = ((128 * th + 8 * q)) ^ swz;         // ^ (mt<<5) per mt

    // Q fragments in registers: rows s0 + 32g + 16nt + lm
    short8 qf[2][2];
#pragma unroll
    for (int nt = 0; nt < 2; nt++)
#pragma unroll
        for (int kc = 0; kc < 2; kc++) {
            const ushort_t* qg = Q + base + (size_t)(s0 + 32 * g + 16 * nt + lm) * D_HEAD + kc * 32 + q * 8;
            uint4 u = *(const uint4*)qg;
            qf[nt][kc] = *(const short8*)&u;
        }

    // O^T partials: o[nt][dj], lane holds O[s=s0+32g+16nt+lm][d=16dj+4q+r] (t-half partial)
    float4v o[2][4];
#pragma unroll
    for (int nt = 0; nt < 2; nt++)
#pragma unroll
        for (int dj = 0; dj < 4; dj++) o[nt][dj] = (float4v){0.f, 0.f, 0.f, 0.f};

    const ushort_t* kg0 = Kb + base + (size_t)rK * D_HEAD + (t & 7) * 8;   // global K src
    const ushort_t* vg0 = Vt + base + (size_t)rV * SEQ + (t & 15) * 8;     // global V^T src

    // prologue: tile 0 -> LDS, tile 1 -> regs
    uint4 kr0, kr1, vr0, vr1;
    kr0 = *(const uint4*)(kg0);
    kr1 = *(const uint4*)(kg0 + 64 * D_HEAD);
    vr0 = *(const uint4*)(vg0);
    vr1 = *(const uint4*)(vg0 + 32 * SEQ);
    *(uint4*)(Ks + kOff0) = kr0;
    *(uint4*)(Ks + kOff1) = kr1;
    *(uint4*)(Vs + vOff0) = vr0;
    *(uint4*)(Vs + vOff1) = vr1;
    kr0 = *(const uint4*)(kg0 + 128 * D_HEAD);
    kr1 = *(const uint4*)(kg0 + 192 * D_HEAD);
    vr0 = *(const uint4*)(vg0 + 128);
    vr1 = *(const uint4*)(vg0 + 32 * SEQ + 128);
    __syncthreads();

    for (int tt = 0; tt < NIT; tt++) {
        int cur = tt & 1;
        const char* ksb = Ks + cur * KBUF;
        const char* vsb = Vs + cur * VBUF;

        // --- issue-early: commit reg-staged tile tt+1 to other buffer; prefetch tt+2 ---
        if (tt + 1 < NIT) {
            int nxt = 1 - cur;
            *(uint4*)(Ks + nxt * KBUF + kOff0) = kr0;
            *(uint4*)(Ks + nxt * KBUF + kOff1) = kr1;
            *(uint4*)(Vs + nxt * VBUF + vOff0) = vr0;
            *(uint4*)(Vs + nxt * VBUF + vOff1) = vr1;
            if (tt + 2 < NIT) {
                size_t ko = (size_t)(tt + 2) * 128 * D_HEAD;
                size_t vo = (size_t)(tt + 2) * 128;
                kr0 = *(const uint4*)(kg0 + ko);
                kr1 = *(const uint4*)(kg0 + ko + 64 * D_HEAD);
                vr0 = *(const uint4*)(vg0 + vo);
                vr1 = *(const uint4*)(vg0 + vo + 32 * SEQ);
            }
        }

        // --- mt-rotation pipeline: QK^T(mt) overlaps sigmoid+PV(mt-1) ---
        const char* vrow = vsb + vRowB;
        float4v st[2][2];                              // [mt&1][nt], static rotation
        qkt_step(ksb, kRow0, kc0, kc1, qf, st[0]);
#pragma unroll
        for (int mt = 1; mt < 4; mt++) {
            qkt_step(ksb, kRow0 + 2048 * mt, kc0, kc1, qf, st[mt & 1]);
            sig_pv(vrow, vColBase ^ ((mt - 1) << 5), st[(mt - 1) & 1], o);
        }
        sig_pv(vrow, vColBase ^ (3 << 5), st[1], o);

        __syncthreads();
    }

    // --- pair-wave O reduction into Osum (float4; stride 68 keeps 16B alignment) ---
    if (th == 0) {
#pragma unroll
        for (int nt = 0; nt < 2; nt++)
#pragma unroll
            for (int dj = 0; dj < 4; dj++) {
                float4v v = o[nt][dj];
                *(float4*)&Osum[(32 * g + 16 * nt + lm) * 68 + 16 * dj + 4 * q] =
                    make_float4(v[0], v[1], v[2], v[3]);
            }
    }
    __syncthreads();
    if (th == 1) {
#pragma unroll
        for (int nt = 0; nt < 2; nt++)
#pragma unroll
            for (int dj = 0; dj < 4; dj++) {
                float* p = &Osum[(32 * g + 16 * nt + lm) * 68 + 16 * dj + 4 * q];
                float4 old = *(float4*)p;
                float4v v = o[nt][dj];
                *(float4*)p = make_float4(old.x + v[0], old.y + v[1], old.z + v[2], old.w + v[3]);
            }
    }
    __syncthreads();

    // --- epilogue: Y = X + O (thread t: row t>>2, 16 cols) ---
    {
        int row = t >> 2, c0 = (t & 3) * 16;
        size_t gro = ((size_t)(b * SEQ + s0 + row)) * D_MODEL + h * D_HEAD + c0;
        const float* xp = X + gro;
        float* yp = Y + gro;
        const float* os = &Osum[row * 68 + c0];
#pragma unroll
        for (int i = 0; i < 4; i++) {
            float4 xv = *(const float4*)(xp + i * 4);
            float4 ov = *(const float4*)(os + i * 4);
            float4 rr;
            rr.x = xv.x + ov.x; rr.y = xv.y + ov.y;
            rr.z = xv.z + ov.z; rr.w = xv.w + ov.w;
            *(float4*)(yp + i * 4) = rr;
        }
    }
}

extern "C" void kernel_launch(void* const* d_in, const int* in_sizes, int n_in,
                              void* d_out, int out_size, void* d_ws, size_t ws_size,
                              hipStream_t stream) {
    const float* x   = (const float*)d_in[0];
    const float* Wq  = (const float*)d_in[1];
    const float* bq  = (const float*)d_in[2];
    const float* Wk  = (const float*)d_in[3];
    const float* bk  = (const float*)d_in[4];
    const float* Wv  = (const float*)d_in[5];
    const float* bv  = (const float*)d_in[6];
    const float* W1  = (const float*)d_in[7];
    const float* b1  = (const float*)d_in[8];
    const float* W2  = (const float*)d_in[9];
    const float* b2  = (const float*)d_in[10];
    const float* g1  = (const float*)d_in[11];
    const float* be1 = (const float*)d_in[12];
    const float* g2  = (const float*)d_in[13];
    const float* be2 = (const float*)d_in[14];
    float* out = (float*)d_out;

    char* p = (char*)d_ws;
    ushort_t* xn    = (ushort_t*)p; p += (size_t)NTOK * D_MODEL * 2;
    ushort_t* yn    = (ushort_t*)p; p += (size_t)NTOK * D_MODEL * 2;
    float*    y     = (float*)p;    p += (size_t)NTOK * D_MODEL * 4;
    ushort_t* qb    = (ushort_t*)p; p += (size_t)NTOK * D_MODEL * 2;
    ushort_t* kb    = (ushort_t*)p; p += (size_t)NTOK * D_MODEL * 2;
    ushort_t* vt    = (ushort_t*)p; p += (size_t)NTOK * D_MODEL * 2;
    ushort_t* hb    = (ushort_t*)p; p += (size_t)NTOK * D_FF * 2;
    ushort_t* Wqkvt = (ushort_t*)p; p += (size_t)3 * D_MODEL * D_MODEL * 2;
    ushort_t* W1t   = (ushort_t*)p; p += (size_t)D_MODEL * D_FF * 2;
    ushort_t* W2t   = (ushort_t*)p; p += (size_t)D_FF * D_MODEL * 2;

    k_prep_weights<<<704, 256, 0, stream>>>(Wq, Wk, Wv, W1, W2, Wqkvt, W1t, W2t);

    k_layernorm<<<NTOK / 4, 256, 0, stream>>>(x, g1, be1, xn);

    dim3 gq(NTOK / 128, (3 * D_MODEL) / 128);
    k_gemm_qkv<<<gq, 256, 0, stream>>>(xn, Wqkvt, bq, bk, bv, qb, kb, vt);

    dim3 ga(SEQ / 128, BATCH * N_HEADS);
    k_attention<<<ga, 512, 0, stream>>>(qb, kb, vt, x, y);

    k_layernorm<<<NTOK / 4, 256, 0, stream>>>(y, g2, be2, yn);

    dim3 g1d(NTOK / 128, D_FF / 128);
    k_gemm_ffn1<<<g1d, 256, 0, stream>>>(yn, W1t, b1, hb);
    dim3 g2d(NTOK / 128, D_MODEL / 64);
    k_gemm_ffn2<<<g2d, 256, 0, stream>>>(hb, W2t, b2, y, out);
}

// Round 10
// 244.702 us; speedup vs baseline: 1.4914x; 1.0080x over previous
//
#include <hip/hip_runtime.h>
#include <hip/hip_bf16.h>
#include <math.h>

#define D_MODEL 512
#define N_HEADS 8
#define D_HEAD 64
#define D_FF 2048
#define SEQ 2048
#define BATCH 4
#define NTOK (BATCH * SEQ)
#define QSCALE 0.04419417382415922f          // 1/sqrt(512)
#define QSCALE_L2E (-QSCALE * 1.44269504089f) // fold -log2(e)*scale into Q

typedef unsigned short ushort_t;
typedef __attribute__((ext_vector_type(8))) short short8;
typedef __attribute__((ext_vector_type(4))) short short4v;
typedef __attribute__((ext_vector_type(4))) float float4v;

static __device__ __forceinline__ ushort_t f2bf(float f) {
    union { float f; unsigned int i; } c; c.f = f;
    unsigned int i = c.i;
    unsigned int r = (i + 0x7FFFu + ((i >> 16) & 1u)) >> 16;   // RNE
    return (ushort_t)r;
}

static __device__ __forceinline__ unsigned int pack2bf(float a, float b) {
    union { __hip_bfloat162 h; unsigned int u; } c;
    c.h = __float22bfloat162_rn(make_float2(a, b));
    return c.u;
}

// sigmoid with scale pre-folded: input st = -s*scale*log2e  ->  1/(1+2^st)
static __device__ __forceinline__ float sig2(float x) {
    return __builtin_amdgcn_rcpf(1.0f + __builtin_amdgcn_exp2f(x));
}

// ------------- weights -> bf16 transposed [N][K], LDS-tiled (coalesced both sides) -------
__global__ __launch_bounds__(256) void k_prep_weights(const float* __restrict__ Wq,
                                                      const float* __restrict__ Wk,
                                                      const float* __restrict__ Wv,
                                                      const float* __restrict__ W1,
                                                      const float* __restrict__ W2,
                                                      ushort_t* __restrict__ Wqkvt,
                                                      ushort_t* __restrict__ W1t,
                                                      ushort_t* __restrict__ W2t) {
    __shared__ ushort_t tile[64][66];
    int bid = blockIdx.x;
    const float* src; ushort_t* dst; int K, N, tk, tn;
    if (bid < 192) {
        int m = bid >> 6, r = bid & 63;
        src = (m == 0) ? Wq : ((m == 1) ? Wk : Wv);
        dst = Wqkvt + (size_t)m * 512 * 512; K = 512; N = 512; tk = r >> 3; tn = r & 7;
    } else if (bid < 448) {
        int r = bid - 192; src = W1; dst = W1t; K = 512; N = 2048; tk = r >> 5; tn = r & 31;
    } else {
        int r = bid - 448; src = W2; dst = W2t; K = 2048; N = 512; tk = r >> 3; tn = r & 7;
    }
    int k0 = tk * 64, n0 = tn * 64;
    int rr = threadIdx.x >> 6, c = threadIdx.x & 63;
#pragma unroll
    for (int i = 0; i < 16; i++) {
        int row = i * 4 + rr;
        tile[row][c] = f2bf(src[(size_t)(k0 + row) * N + n0 + c]);
    }
    __syncthreads();
#pragma unroll
    for (int i = 0; i < 16; i++) {
        int row = i * 4 + rr;   // n-local
        dst[(size_t)(n0 + row) * K + k0 + c] = tile[c][row];
    }
}

// ---------------- layernorm: one wave per 512-wide row, out bf16 ----------------
__global__ __launch_bounds__(256) void k_layernorm(const float* __restrict__ X,
                                                   const float* __restrict__ g,
                                                   const float* __restrict__ be,
                                                   ushort_t* __restrict__ Out) {
    int row  = blockIdx.x * 4 + (threadIdx.x >> 6);
    int lane = threadIdx.x & 63;
    const float* x = X + (size_t)row * D_MODEL + lane * 8;
    float4 v0 = ((const float4*)x)[0];
    float4 v1 = ((const float4*)x)[1];
    float vals[8] = {v0.x, v0.y, v0.z, v0.w, v1.x, v1.y, v1.z, v1.w};
    float s = 0.f, sq = 0.f;
#pragma unroll
    for (int j = 0; j < 8; j++) { s += vals[j]; sq += vals[j] * vals[j]; }
#pragma unroll
    for (int off = 32; off; off >>= 1) { s += __shfl_xor(s, off); sq += __shfl_xor(sq, off); }
    float mu  = s * (1.0f / D_MODEL);
    float var = sq * (1.0f / D_MODEL) - mu * mu;
    float inv = rsqrtf(var + 1e-5f);
    const float* gp  = g  + lane * 8;
    const float* bp  = be + lane * 8;
    float4 g0 = ((const float4*)gp)[0], g1v = ((const float4*)gp)[1];
    float4 b0 = ((const float4*)bp)[0], b1v = ((const float4*)bp)[1];
    float gs[8] = {g0.x, g0.y, g0.z, g0.w, g1v.x, g1v.y, g1v.z, g1v.w};
    float bs[8] = {b0.x, b0.y, b0.z, b0.w, b1v.x, b1v.y, b1v.z, b1v.w};
    ushort_t o[8];
#pragma unroll
    for (int j = 0; j < 8; j++) o[j] = f2bf((vals[j] - mu) * inv * gs[j] + bs[j]);
    ushort_t* op = Out + (size_t)row * D_MODEL + lane * 8;
    *(uint4*)op = *(uint4*)o;
}

// ======== m97-style GEMM core: 128xBN tile, BK=32, global_load_lds double-buffer =========
static __device__ __forceinline__ void stage_tile(const ushort_t* __restrict__ G, int K,
                                                  ushort_t* L, int nchunks, int koff,
                                                  int w, int l) {
#pragma unroll
    for (int n = w; n < nchunks; n += 4) {
        const ushort_t* g = G + (size_t)(n * 16 + (l >> 2)) * K + koff + (l & 3) * 8;
        __builtin_amdgcn_global_load_lds((const __attribute__((address_space(1))) void*)g,
                                         (__attribute__((address_space(3))) void*)(L + n * 512),
                                         16, 0, 0);
    }
}

template <int JW>
static __device__ __forceinline__ void gemm_core2(const ushort_t* __restrict__ A,
                                                  const ushort_t* __restrict__ Bt,
                                                  int K, int m0, int n0,
                                                  ushort_t* As, ushort_t* Bs,
                                                  float4v acc[4][JW]) {
    const int BBUF = JW * 1024;
    int t = threadIdx.x, w = t >> 6, l = t & 63, q = l >> 4, lm = l & 15;
    int mb = (w & 1) * 64, nb = (w >> 1) * (JW * 16);
    const ushort_t* Ab = A + (size_t)m0 * K;
    const ushort_t* Bb = Bt + (size_t)n0 * K;
    int T = K >> 5;

    stage_tile(Ab, K, As, 8, 0, w, l);
    stage_tile(Bb, K, Bs, 2 * JW, 0, w, l);
    __syncthreads();

    for (int kt = 0; kt < T; kt++) {
        int cur = kt & 1;
        if (kt + 1 < T) {
            stage_tile(Ab, K, As + (1 - cur) * 4096, 8, (kt + 1) * 32, w, l);
            stage_tile(Bb, K, Bs + (1 - cur) * BBUF, 2 * JW, (kt + 1) * 32, w, l);
        }
        const ushort_t* asb = As + cur * 4096;
        const ushort_t* bsb = Bs + cur * BBUF;
        short8 a[4], b[JW];
#pragma unroll
        for (int i = 0; i < 4; i++) a[i] = *(const short8*)&asb[(mb + 16 * i + lm) * 32 + q * 8];
#pragma unroll
        for (int j = 0; j < JW; j++) b[j] = *(const short8*)&bsb[(nb + 16 * j + lm) * 32 + q * 8];
#pragma unroll
        for (int i = 0; i < 4; i++)
#pragma unroll
            for (int j = 0; j < JW; j++)
                acc[i][j] = __builtin_amdgcn_mfma_f32_16x16x32_bf16(a[i], b[j], acc[i][j], 0, 0, 0);
        __syncthreads();
    }
}

// ---------------- fused QKV projection (N=1536): q,k head-layout; v transposed ------------
__global__ __launch_bounds__(256) void k_gemm_qkv(const ushort_t* __restrict__ A,
                                                  const ushort_t* __restrict__ Bt,
                                                  const float* __restrict__ bq,
                                                  const float* __restrict__ bk,
                                                  const float* __restrict__ bv,
                                                  ushort_t* __restrict__ qb,
                                                  ushort_t* __restrict__ kb,
                                                  ushort_t* __restrict__ vt) {
    __shared__ __align__(16) ushort_t As[8192];
    __shared__ __align__(16) ushort_t Bs[8192];
    int m0 = blockIdx.x * 128, n0 = blockIdx.y * 128;
    float4v acc[4][4];
#pragma unroll
    for (int i = 0; i < 4; i++)
#pragma unroll
        for (int j = 0; j < 4; j++) acc[i][j] = (float4v){0.f, 0.f, 0.f, 0.f};
    gemm_core2<4>(A, Bt, D_MODEL, m0, n0, As, Bs, acc);

    int t = threadIdx.x, w = t >> 6, l = t & 63, q = l >> 4, lm = l & 15;
    int mb = (w & 1) * 64, nb = (w >> 1) * 64;
    int mat = n0 >> 9, c0 = n0 & 511;
    const float* bias = (mat == 0) ? bq : ((mat == 1) ? bk : bv);
#pragma unroll
    for (int j = 0; j < 4; j++) {
        int cl = c0 + nb + 16 * j + lm;
        int hh = cl >> 6, dh = cl & 63;
        float bvv = bias[cl];
#pragma unroll
        for (int i = 0; i < 4; i++) {
            int mr0 = m0 + mb + 16 * i + q * 4;
            int bb = mr0 >> 11, ss0 = mr0 & (SEQ - 1);
            if (mat == 2) {
                union { ushort_t s[4]; uint2 v; } pk;
#pragma unroll
                for (int r = 0; r < 4; r++) pk.s[r] = f2bf(acc[i][j][r] + bvv);
                *(uint2*)&vt[((size_t)(bb * N_HEADS + hh) * D_HEAD + dh) * SEQ + ss0] = pk.v;
            } else {
                ushort_t* dst = (mat == 0) ? qb : kb;
                float sc = (mat == 0) ? QSCALE_L2E : 1.0f;
#pragma unroll
                for (int r = 0; r < 4; r++)
                    dst[((size_t)(bb * N_HEADS + hh) * SEQ + ss0 + r) * D_HEAD + dh] =
                        f2bf((acc[i][j][r] + bvv) * sc);
            }
        }
    }
}

// ---------------- FFN1: relu(yn @ W1 + b1) -> bf16 row-major ------------------------------
__global__ __launch_bounds__(256) void k_gemm_ffn1(const ushort_t* __restrict__ A,
                                                   const ushort_t* __restrict__ Bt,
                                                   const float* __restrict__ b1,
                                                   ushort_t* __restrict__ hb) {
    __shared__ __align__(16) ushort_t As[8192];
    __shared__ __align__(16) ushort_t Bs[8192];
    int m0 = blockIdx.x * 128, n0 = blockIdx.y * 128;
    float4v acc[4][4];
#pragma unroll
    for (int i = 0; i < 4; i++)
#pragma unroll
        for (int j = 0; j < 4; j++) acc[i][j] = (float4v){0.f, 0.f, 0.f, 0.f};
    gemm_core2<4>(A, Bt, D_MODEL, m0, n0, As, Bs, acc);

    int t = threadIdx.x, w = t >> 6, l = t & 63, q = l >> 4, lm = l & 15;
    int mb = (w & 1) * 64, nb = (w >> 1) * 64;
#pragma unroll
    for (int j = 0; j < 4; j++) {
        int cl = n0 + nb + 16 * j + lm;
        float bvv = b1[cl];
#pragma unroll
        for (int i = 0; i < 4; i++) {
            int mr0 = m0 + mb + 16 * i + q * 4;
#pragma unroll
            for (int r = 0; r < 4; r++)
                hb[(size_t)(mr0 + r) * D_FF + cl] = f2bf(fmaxf(acc[i][j][r] + bvv, 0.f));
        }
    }
}

// ---------------- FFN2: hb @ W2 + b2 + residual -> f32 out (128x64 tile) ------------------
__global__ __launch_bounds__(256) void k_gemm_ffn2(const ushort_t* __restrict__ A,
                                                   const ushort_t* __restrict__ Bt,
                                                   const float* __restrict__ b2,
                                                   const float* __restrict__ res,
                                                   float* __restrict__ out) {
    __shared__ __align__(16) ushort_t As[8192];
    __shared__ __align__(16) ushort_t Bs[4096];
    int m0 = blockIdx.x * 128, n0 = blockIdx.y * 64;
    float4v acc[4][2];
#pragma unroll
    for (int i = 0; i < 4; i++)
#pragma unroll
        for (int j = 0; j < 2; j++) acc[i][j] = (float4v){0.f, 0.f, 0.f, 0.f};
    gemm_core2<2>(A, Bt, D_FF, m0, n0, As, Bs, acc);

    int t = threadIdx.x, w = t >> 6, l = t & 63, q = l >> 4, lm = l & 15;
    int mb = (w & 1) * 64, nb = (w >> 1) * 32;
#pragma unroll
    for (int j = 0; j < 2; j++) {
        int cl = n0 + nb + 16 * j + lm;
        float bvv = b2[cl];
#pragma unroll
        for (int i = 0; i < 4; i++) {
            int mr0 = m0 + mb + 16 * i + q * 4;
#pragma unroll
            for (int r = 0; r < 4; r++) {
                size_t idx = (size_t)(mr0 + r) * D_MODEL + cl;
                out[idx] = acc[i][j][r] + bvv + res[idx];
            }
        }
    }
}

// ---- attention helpers (byte-addressed, XOR-swizzled LDS; nt=4 wide) ---------------------
static __device__ __forceinline__ void qkt_step4(const char* __restrict__ ksb, int rowByte,
                                                 int c0, int c1,
                                                 const short8 qf[4][2], float4v st[4]) {
    short8 kf0 = *(const short8*)(ksb + rowByte + c0);
    short8 kf1 = *(const short8*)(ksb + rowByte + c1);
#pragma unroll
    for (int nt = 0; nt < 4; nt++) {
        float4v z = (float4v){0.f, 0.f, 0.f, 0.f};
        z = __builtin_amdgcn_mfma_f32_16x16x32_bf16(kf0, qf[nt][0], z, 0, 0, 0);
        z = __builtin_amdgcn_mfma_f32_16x16x32_bf16(kf1, qf[nt][1], z, 0, 0, 0);
        st[nt] = z;
    }
}

static __device__ __forceinline__ void sig_pv4(const char* __restrict__ vrow, int vcol,
                                               const float4v st[4], float4v o[4][4]) {
    short4v pf[4];
#pragma unroll
    for (int nt = 0; nt < 4; nt++) {
        union { unsigned int u[2]; short4v v; } pk;
        pk.u[0] = pack2bf(sig2(st[nt][0]), sig2(st[nt][1]));
        pk.u[1] = pack2bf(sig2(st[nt][2]), sig2(st[nt][3]));
        pf[nt] = pk.v;
    }
#pragma unroll
    for (int dj = 0; dj < 4; dj++) {
        short4v vf = *(const short4v*)(vrow + dj * 4096 + vcol);
#pragma unroll
        for (int nt = 0; nt < 4; nt++)
            o[nt][dj] = __builtin_amdgcn_mfma_f32_16x16x16bf16_1k(vf, pf[nt], o[nt][dj], 0, 0, 0);
    }
}

// ---------------- fused sigmoid attention v13: 64 Q-rows/wave (2x amortization) -----------
// THEORY: 7 experiments showed per-CU throughput invariant under schedule changes ->
// issue-throughput-bound. The only lever: fewer instructions per unit work. nt 2->4
// (wave covers 64 Q-rows) shares each K-frag read, V-frag read, staging op and loop
// overhead across 2x the Q-work; MFMA and sigmoid per-work unchanged.
// Block = 256 Q-rows (4 g-groups x 64), 8 waves (g=w>>1, th=w&1), grid (8,32)=256 -> 1/CU,
// 2 waves/SIMD (occupancy proven non-binding in v8/v9; this doubles as the A/B test).
// K/V staging + st_swizzle identical to v12. Osum 256x68 f32 = 69.6 KB (aliases loop LDS).
__global__ __launch_bounds__(512, 2) void k_attention(const ushort_t* __restrict__ Q,
                                                      const ushort_t* __restrict__ Kb,
                                                      const ushort_t* __restrict__ Vt,
                                                      const float* __restrict__ X,
                                                      float* __restrict__ Y) {
    __shared__ __align__(16) char smem[69632];
    char* Ks = smem;                                   // [2][128 rows][128B] swizzled
    char* Vs = smem + 32768;                           // [2][64 rows][256B] swizzled (V^T)
    float* Osum = (float*)smem;                        // after loop: 256 x 68 f32 (69.6 KB)

    const int KBUF = 16384;                            // bytes per K buffer
    const int VBUF = 16384;                            // bytes per V buffer
    const int NIT  = SEQ / 128;                        // 16

    int bh = blockIdx.y;
    int b = bh >> 3, h = bh & 7;
    size_t base = (size_t)bh * SEQ * D_HEAD;
    int s0 = blockIdx.x * 256;
    int t = threadIdx.x, w = t >> 6, l = t & 63, q = l >> 4, lm = l & 15;
    int g = w >> 1, th = w & 1;

    // staging (write) offsets, loop-invariant, swizzled (identical to v12)
    int rK = t >> 3;                                   // K shot row (0..63)
    int kOff0 = rK * 128 + (((t & 7) * 16) ^ ((rK & 7) << 4));
    int kOff1 = kOff0 + 8192;                          // +64 rows, same (row&7)
    int rV = t >> 4;                                   // V shot row (0..31)
    int vOff0 = rV * 256 + (((t & 15) * 16) ^ ((rV & 7) << 4));
    int vOff1 = vOff0 + 8192;                          // +32 rows, same (row&7)

    // read offsets, swizzled
    int swz = (lm & 7) << 4;
    int kRow0 = (64 * th + lm) * 128;                  // + mt*2048
    int kc0 = (q * 16) ^ swz;
    int kc1 = kc0 ^ 64;
    int vRowB = lm * 256;                              // + dj*4096 inside sig_pv4
    int vColBase = ((128 * th + 8 * q)) ^ swz;         // ^ (mt<<5) per mt

    // Q fragments in registers: rows s0 + 64g + 16nt + lm  (nt = 0..3)
    short8 qf[4][2];
#pragma unroll
    for (int nt = 0; nt < 4; nt++)
#pragma unroll
        for (int kc = 0; kc < 2; kc++) {
            const ushort_t* qg = Q + base + (size_t)(s0 + 64 * g + 16 * nt + lm) * D_HEAD + kc * 32 + q * 8;
            uint4 u = *(const uint4*)qg;
            qf[nt][kc] = *(const short8*)&u;
        }

    // O^T partials: o[nt][dj], lane holds O[s=s0+64g+16nt+lm][d=16dj+4q+r] (t-half partial)
    float4v o[4][4];
#pragma unroll
    for (int nt = 0; nt < 4; nt++)
#pragma unroll
        for (int dj = 0; dj < 4; dj++) o[nt][dj] = (float4v){0.f, 0.f, 0.f, 0.f};

    const ushort_t* kg0 = Kb + base + (size_t)rK * D_HEAD + (t & 7) * 8;   // global K src
    const ushort_t* vg0 = Vt + base + (size_t)rV * SEQ + (t & 15) * 8;     // global V^T src

    // prologue: tile 0 -> LDS, tile 1 -> regs
    uint4 kr0, kr1, vr0, vr1;
    kr0 = *(const uint4*)(kg0);
    kr1 = *(const uint4*)(kg0 + 64 * D_HEAD);
    vr0 = *(const uint4*)(vg0);
    vr1 = *(const uint4*)(vg0 + 32 * SEQ);
    *(uint4*)(Ks + kOff0) = kr0;
    *(uint4*)(Ks + kOff1) = kr1;
    *(uint4*)(Vs + vOff0) = vr0;
    *(uint4*)(Vs + vOff1) = vr1;
    kr0 = *(const uint4*)(kg0 + 128 * D_HEAD);
    kr1 = *(const uint4*)(kg0 + 192 * D_HEAD);
    vr0 = *(const uint4*)(vg0 + 128);
    vr1 = *(const uint4*)(vg0 + 32 * SEQ + 128);
    __syncthreads();

    for (int tt = 0; tt < NIT; tt++) {
        int cur = tt & 1;
        const char* ksb = Ks + cur * KBUF;
        const char* vsb = Vs + cur * VBUF;

        // --- issue-early: commit reg-staged tile tt+1 to other buffer; prefetch tt+2 ---
        if (tt + 1 < NIT) {
            int nxt = 1 - cur;
            *(uint4*)(Ks + nxt * KBUF + kOff0) = kr0;
            *(uint4*)(Ks + nxt * KBUF + kOff1) = kr1;
            *(uint4*)(Vs + nxt * VBUF + vOff0) = vr0;
            *(uint4*)(Vs + nxt * VBUF + vOff1) = vr1;
            if (tt + 2 < NIT) {
                size_t ko = (size_t)(tt + 2) * 128 * D_HEAD;
                size_t vo = (size_t)(tt + 2) * 128;
                kr0 = *(const uint4*)(kg0 + ko);
                kr1 = *(const uint4*)(kg0 + ko + 64 * D_HEAD);
                vr0 = *(const uint4*)(vg0 + vo);
                vr1 = *(const uint4*)(vg0 + vo + 32 * SEQ);
            }
        }

        // --- mt-rotation pipeline: QK^T(mt) overlaps sigmoid+PV(mt-1) ---
        const char* vrow = vsb + vRowB;
        float4v st[2][4];                              // [mt&1][nt], static rotation
        qkt_step4(ksb, kRow0, kc0, kc1, qf, st[0]);
#pragma unroll
        for (int mt = 1; mt < 4; mt++) {
            qkt_step4(ksb, kRow0 + 2048 * mt, kc0, kc1, qf, st[mt & 1]);
            sig_pv4(vrow, vColBase ^ ((mt - 1) << 5), st[(mt - 1) & 1], o);
        }
        sig_pv4(vrow, vColBase ^ (3 << 5), st[1], o);

        __syncthreads();
    }

    // --- pair-wave O reduction into Osum (float4; stride 68 keeps 16B alignment) ---
    if (th == 0) {
#pragma unroll
        for (int nt = 0; nt < 4; nt++)
#pragma unroll
            for (int dj = 0; dj < 4; dj++) {
                float4v v = o[nt][dj];
                *(float4*)&Osum[(64 * g + 16 * nt + lm) * 68 + 16 * dj + 4 * q] =
                    make_float4(v[0], v[1], v[2], v[3]);
            }
    }
    __syncthreads();
    if (th == 1) {
#pragma unroll
        for (int nt = 0; nt < 4; nt++)
#pragma unroll
            for (int dj = 0; dj < 4; dj++) {
                float* p = &Osum[(64 * g + 16 * nt + lm) * 68 + 16 * dj + 4 * q];
                float4 old = *(float4*)p;
                float4v v = o[nt][dj];
                *(float4*)p = make_float4(old.x + v[0], old.y + v[1], old.z + v[2], old.w + v[3]);
            }
    }
    __syncthreads();

    // --- epilogue: Y = X + O (256 rows x 64 cols; thread t: row t>>1, 32 cols) ---
    {
        int row = t >> 1, c0 = (t & 1) * 32;
        size_t gro = ((size_t)(b * SEQ + s0 + row)) * D_MODEL + h * D_HEAD + c0;
        const float* xp = X + gro;
        float* yp = Y + gro;
        const float* os = &Osum[row * 68 + c0];
#pragma unroll
        for (int i = 0; i < 8; i++) {
            float4 xv = *(const float4*)(xp + i * 4);
            float4 ov = *(const float4*)(os + i * 4);
            float4 rr;
            rr.x = xv.x + ov.x; rr.y = xv.y + ov.y;
            rr.z = xv.z + ov.z; rr.w = xv.w + ov.w;
            *(float4*)(yp + i * 4) = rr;
        }
    }
}

extern "C" void kernel_launch(void* const* d_in, const int* in_sizes, int n_in,
                              void* d_out, int out_size, void* d_ws, size_t ws_size,
                              hipStream_t stream) {
    const float* x   = (const float*)d_in[0];
    const float* Wq  = (const float*)d_in[1];
    const float* bq  = (const float*)d_in[2];
    const float* Wk  = (const float*)d_in[3];
    const float* bk  = (const float*)d_in[4];
    const float* Wv  = (const float*)d_in[5];
    const float* bv  = (const float*)d_in[6];
    const float* W1  = (const float*)d_in[7];
    const float* b1  = (const float*)d_in[8];
    const float* W2  = (const float*)d_in[9];
    const float* b2  = (const float*)d_in[10];
    const float* g1  = (const float*)d_in[11];
    const float* be1 = (const float*)d_in[12];
    const float* g2  = (const float*)d_in[13];
    const float* be2 = (const float*)d_in[14];
    float* out = (float*)d_out;

    char* p = (char*)d_ws;
    ushort_t* xn    = (ushort_t*)p; p += (size_t)NTOK * D_MODEL * 2;
    ushort_t* yn    = (ushort_t*)p; p += (size_t)NTOK * D_MODEL * 2;
    float*    y     = (float*)p;    p += (size_t)NTOK * D_MODEL * 4;
    ushort_t* qb    = (ushort_t*)p; p += (size_t)NTOK * D_MODEL * 2;
    ushort_t* kb    = (ushort_t*)p; p += (size_t)NTOK * D_MODEL * 2;
    ushort_t* vt    = (ushort_t*)p; p += (size_t)NTOK * D_MODEL * 2;
    ushort_t* hb    = (ushort_t*)p; p += (size_t)NTOK * D_FF * 2;
    ushort_t* Wqkvt = (ushort_t*)p; p += (size_t)3 * D_MODEL * D_MODEL * 2;
    ushort_t* W1t   = (ushort_t*)p; p += (size_t)D_MODEL * D_FF * 2;
    ushort_t* W2t   = (ushort_t*)p; p += (size_t)D_FF * D_MODEL * 2;

    k_prep_weights<<<704, 256, 0, stream>>>(Wq, Wk, Wv, W1, W2, Wqkvt, W1t, W2t);

    k_layernorm<<<NTOK / 4, 256, 0, stream>>>(x, g1, be1, xn);

    dim3 gq(NTOK / 128, (3 * D_MODEL) / 128);
    k_gemm_qkv<<<gq, 256, 0, stream>>>(xn, Wqkvt, bq, bk, bv, qb, kb, vt);

    dim3 ga(SEQ / 256, BATCH * N_HEADS);
    k_attention<<<ga, 512, 0, stream>>>(qb, kb, vt, x, y);

    k_layernorm<<<NTOK / 4, 256, 0, stream>>>(y, g2, be2, yn);

    dim3 g1d(NTOK / 128, D_FF / 128);
    k_gemm_ffn1<<<g1d, 256, 0, stream>>>(yn, W1t, b1, hb);
    dim3 g2d(NTOK / 128, D_MODEL / 64);
    k_gemm_ffn2<<<g2d, 256, 0, stream>>>(hb, W2t, b2, y, out);
}